// Round 18
// baseline (600.790 us; speedup 1.0000x reference)
//
#include <hip/hip_runtime.h>
#include <hip/hip_fp16.h>

typedef unsigned short u16;
typedef __attribute__((ext_vector_type(8))) short bf16x8;
typedef __attribute__((ext_vector_type(4))) float f32x4;
typedef __attribute__((ext_vector_type(4))) unsigned short u16x4;

#define NMAT 17

__device__ __forceinline__ u16 f2bf(float f) {
    union { float f; unsigned u; } a; a.f = f;
    unsigned u = a.u;
    return (u16)((u + (((u >> 16) & 1u) + 0x7fffu)) >> 16);
}
__device__ __forceinline__ float bf2f(u16 v) {
    union { unsigned u; float f; } a; a.u = ((unsigned)v) << 16;
    return a.f;
}

// ---------------- weight prep: W[K][64] f32 -> Wt[64][K] bf16 ----------------
struct PrepArgs { const float* src[NMAT]; int dstoff[NMAT]; int K[NMAT]; };

__global__ __launch_bounds__(256) void prep_weights(PrepArgs a, u16* __restrict__ pool) {
    int m = blockIdx.x >> 6;
    int idx = (blockIdx.x & 63) * 256 + threadIdx.x;
    int K = a.K[m];
    if (idx < K * 64) {
        int col = idx / K, k = idx - col * K;
        pool[a.dstoff[m] + idx] = f2bf(a.src[m][(size_t)k * 64 + col]);
    }
}

// ------- node init, BOTH tables; also zero-inits the conv accumulator -------
__global__ __launch_bounds__(512) void node_init_both(
    const float* __restrict__ emb_u, const int* __restrict__ nid_u, int NU_,
    const float* __restrict__ emb_b, const int* __restrict__ nid_b, int NB_, int nTu,
    const u16* __restrict__ W1u, const float* __restrict__ b1u,
    const u16* __restrict__ W2u, const float* __restrict__ b2u,
    const u16* __restrict__ W1b, const float* __restrict__ b1b,
    const u16* __restrict__ W2b, const float* __restrict__ b2b,
    u16* __restrict__ hbf, __half* __restrict__ conv)
{
    __shared__ u16 sW1[64 * 72], sW2[64 * 72], sHid[128 * 72];
    const int tid = threadIdx.x;
    const int wv = tid >> 6, lane = tid & 63;
    const int lr = lane & 15, lk = lane >> 4;

    int t = blockIdx.x;
    const bool isB = t >= nTu;
    if (isB) t -= nTu;
    const int N = isB ? NB_ : NU_;
    const int rowoff = isB ? NU_ : 0;
    const float* emb = isB ? emb_b : emb_u;
    const int* nid = isB ? nid_b : nid_u;
    const u16* W1 = isB ? W1b : W1u;
    const u16* W2 = isB ? W2b : W2u;
    const float* b1 = isB ? b1b : b1u;
    const float* b2 = isB ? b2b : b2u;

    for (int c = tid; c < 512; c += 512) {
        int row = c >> 3, cc = c & 7;
        *(bf16x8*)&sW1[row * 72 + cc * 8] = *(const bf16x8*)&W1[row * 64 + cc * 8];
        *(bf16x8*)&sW2[row * 72 + cc * 8] = *(const bf16x8*)&W2[row * 64 + cc * 8];
    }
    // zero conv rows for this tile
    const int rb0 = t * 128;
    const f32x4 zv = (f32x4){0.f, 0.f, 0.f, 0.f};
#pragma unroll
    for (int c = tid; c < 1024; c += 512) {
        int row = rb0 + (c >> 3), cc = c & 7;
        if (row < N)
            ((f32x4*)&conv[(size_t)(rowoff + row) * 64])[cc] = zv;
    }
    float b1v[4], b2v[4];
#pragma unroll
    for (int n = 0; n < 4; ++n) { b1v[n] = b1[lr + 16 * n]; b2v[n] = b2[lr + 16 * n]; }

    const int rb = t * 128 + wv * 16;
    int ar = rb + lr; if (ar >= N) ar = N - 1;
    const int g = nid[ar];
    const float* ap = emb + (size_t)g * 64 + lk * 8;
    bf16x8 afr[2];
#pragma unroll
    for (int ks = 0; ks < 2; ++ks) {
        f32x4 lo = *(const f32x4*)(ap + ks * 32);
        f32x4 hi = *(const f32x4*)(ap + ks * 32 + 4);
        bf16x8 v;
        v[0] = (short)f2bf(lo[0]); v[1] = (short)f2bf(lo[1]);
        v[2] = (short)f2bf(lo[2]); v[3] = (short)f2bf(lo[3]);
        v[4] = (short)f2bf(hi[0]); v[5] = (short)f2bf(hi[1]);
        v[6] = (short)f2bf(hi[2]); v[7] = (short)f2bf(hi[3]);
        afr[ks] = v;
    }
    __syncthreads();
    f32x4 acc[4];
#pragma unroll
    for (int n = 0; n < 4; ++n) acc[n] = (f32x4){b1v[n], b1v[n], b1v[n], b1v[n]};
#pragma unroll
    for (int ks = 0; ks < 2; ++ks) {
#pragma unroll
        for (int n = 0; n < 4; ++n) {
            bf16x8 bfr = *(const bf16x8*)&sW1[(lr + 16 * n) * 72 + ks * 32 + lk * 8];
            acc[n] = __builtin_amdgcn_mfma_f32_16x16x32_bf16(afr[ks], bfr, acc[n], 0, 0, 0);
        }
    }
#pragma unroll
    for (int n = 0; n < 4; ++n)
#pragma unroll
        for (int i = 0; i < 4; ++i)
            sHid[(wv * 16 + lk * 4 + i) * 72 + lr + 16 * n] = f2bf(fmaxf(acc[n][i], 0.f));
    __syncthreads();
    f32x4 a2[4];
#pragma unroll
    for (int n = 0; n < 4; ++n) a2[n] = (f32x4){b2v[n], b2v[n], b2v[n], b2v[n]};
#pragma unroll
    for (int ks = 0; ks < 2; ++ks) {
        bf16x8 af = *(const bf16x8*)&sHid[(wv * 16 + lr) * 72 + ks * 32 + lk * 8];
#pragma unroll
        for (int n = 0; n < 4; ++n) {
            bf16x8 bfr = *(const bf16x8*)&sW2[(lr + 16 * n) * 72 + ks * 32 + lk * 8];
            a2[n] = __builtin_amdgcn_mfma_f32_16x16x32_bf16(af, bfr, a2[n], 0, 0, 0);
        }
    }
#pragma unroll
    for (int i = 0; i < 4; ++i) {
        int r = rb + lk * 4 + i;
        if (r < N) {
            size_t gr = (size_t)(rowoff + r);
#pragma unroll
            for (int n = 0; n < 4; ++n)
                hbf[gr * 64 + lr + 16 * n] = f2bf(a2[n][i]);
        }
    }
}

// -------- fused edge init: persistent weights, double-buffered sHid ---------
__global__ __launch_bounds__(512) void edge_init_fused(
    const float* __restrict__ attr, int E_,
    const u16* __restrict__ W1u, const float* __restrict__ b1u,
    const u16* __restrict__ W2u, const float* __restrict__ b2u,
    const u16* __restrict__ W1b, const float* __restrict__ b1b,
    const u16* __restrict__ W2b, const float* __restrict__ b2b,
    u16* __restrict__ eu, u16* __restrict__ eb)
{
    __shared__ u16 sW1[2][64 * 264];
    __shared__ u16 sW2[2][64 * 72];
    __shared__ u16 sHid[2][128 * 72];
    const int tid = threadIdx.x;
    const int wv = tid >> 6, lane = tid & 63;
    const int lr = lane & 15, lk = lane >> 4;

    for (int c = tid; c < 4096; c += 512) {
        int d = c >> 11, rem = c & 2047;
        int row = rem >> 5, cc = rem & 31;
        const u16* w = d ? W1b : W1u;
        *(bf16x8*)&sW1[d][row * 264 + cc * 8] = *(const bf16x8*)&w[row * 256 + cc * 8];
    }
    for (int c = tid; c < 1024; c += 512) {
        int d = c >> 9, rem = c & 511;
        int row = rem >> 3, cc = rem & 7;
        const u16* w = d ? W2b : W2u;
        *(bf16x8*)&sW2[d][row * 72 + cc * 8] = *(const bf16x8*)&w[row * 64 + cc * 8];
    }
    float b1v[2][4], b2v[2][4];
#pragma unroll
    for (int n = 0; n < 4; ++n) {
        b1v[0][n] = b1u[lr + 16 * n]; b1v[1][n] = b1b[lr + 16 * n];
        b2v[0][n] = b2u[lr + 16 * n]; b2v[1][n] = b2b[lr + 16 * n];
    }
    __syncthreads();

    const int nT = (E_ + 127) >> 7;
    for (int t = blockIdx.x; t < nT; t += gridDim.x) {
        const int rb = t * 128 + wv * 16;
        int ar = rb + lr; if (ar >= E_) ar = E_ - 1;
        const float* ap = attr + (size_t)ar * 256 + lk * 8;
        bf16x8 afr[8];
#pragma unroll
        for (int ks = 0; ks < 8; ++ks) {
            f32x4 lo = *(const f32x4*)(ap + ks * 32);
            f32x4 hi = *(const f32x4*)(ap + ks * 32 + 4);
            bf16x8 v;
            v[0] = (short)f2bf(lo[0]); v[1] = (short)f2bf(lo[1]);
            v[2] = (short)f2bf(lo[2]); v[3] = (short)f2bf(lo[3]);
            v[4] = (short)f2bf(hi[0]); v[5] = (short)f2bf(hi[1]);
            v[6] = (short)f2bf(hi[2]); v[7] = (short)f2bf(hi[3]);
            afr[ks] = v;
        }
#pragma unroll
        for (int dir = 0; dir < 2; ++dir) {
            f32x4 acc[4];
#pragma unroll
            for (int n = 0; n < 4; ++n) acc[n] = (f32x4){b1v[dir][n], b1v[dir][n], b1v[dir][n], b1v[dir][n]};
#pragma unroll
            for (int ks = 0; ks < 8; ++ks) {
#pragma unroll
                for (int n = 0; n < 4; ++n) {
                    bf16x8 bfr = *(const bf16x8*)&sW1[dir][(lr + 16 * n) * 264 + ks * 32 + lk * 8];
                    acc[n] = __builtin_amdgcn_mfma_f32_16x16x32_bf16(afr[ks], bfr, acc[n], 0, 0, 0);
                }
            }
#pragma unroll
            for (int n = 0; n < 4; ++n)
#pragma unroll
                for (int i = 0; i < 4; ++i)
                    sHid[dir][(wv * 16 + lk * 4 + i) * 72 + lr + 16 * n] = f2bf(fmaxf(acc[n][i], 0.f));
            __syncthreads();
            f32x4 a2[4];
#pragma unroll
            for (int n = 0; n < 4; ++n) a2[n] = (f32x4){b2v[dir][n], b2v[dir][n], b2v[dir][n], b2v[dir][n]};
#pragma unroll
            for (int ks = 0; ks < 2; ++ks) {
                bf16x8 af = *(const bf16x8*)&sHid[dir][(wv * 16 + lr) * 72 + ks * 32 + lk * 8];
#pragma unroll
                for (int n = 0; n < 4; ++n) {
                    bf16x8 bfr = *(const bf16x8*)&sW2[dir][(lr + 16 * n) * 72 + ks * 32 + lk * 8];
                    a2[n] = __builtin_amdgcn_mfma_f32_16x16x32_bf16(af, bfr, a2[n], 0, 0, 0);
                }
            }
            u16* op = dir ? eb : eu;
#pragma unroll
            for (int i = 0; i < 4; ++i) {
                int r = rb + lk * 4 + i;
                if (r < E_) {
#pragma unroll
                    for (int n = 0; n < 4; ++n)
                        op[(size_t)r * 64 + lr + 16 * n] = f2bf(a2[n][i]);
                }
            }
        }
    }
}

// -------- edge messages: weights read from GLOBAL (L1-resident), LDS=sHid only
// LDS 18.4 KB -> occupancy wave-capped at 4 blocks/CU (32 waves, was 24).
// One barrier per block (sHid).
__global__ __launch_bounds__(512) void edge_msg_both(
    const u16* __restrict__ hub, const u16* __restrict__ hbb,
    const int* __restrict__ src, const int* __restrict__ dst,
    const u16* __restrict__ eu, const u16* __restrict__ eb, int E_,
    const u16* __restrict__ W1a, const float* __restrict__ b1a,
    const u16* __restrict__ W2a, const float* __restrict__ b2a,
    const u16* __restrict__ W1b, const float* __restrict__ b1b,
    const u16* __restrict__ W2b, const float* __restrict__ b2b,
    __half* __restrict__ cb, __half* __restrict__ cu)
{
    __shared__ u16 sHid[128 * 72];
    const int tid = threadIdx.x;
    const int wv = tid >> 6, lane = tid & 63;
    const int lr = lane & 15, lk = lane >> 4;

    const int nTe = (E_ + 127) >> 7;
    const int grp = blockIdx.x >> 4, rem = blockIdx.x & 15;
    const int dir = rem >> 3;
    const int t = grp * 8 + (rem & 7);
    if (t >= nTe) return;

    const u16* W1 = dir ? W1b : W1a;
    const u16* W2 = dir ? W2b : W2a;
    const float* b1 = dir ? b1b : b1a;
    const float* b2 = dir ? b2b : b2a;
    const u16* featA = dir ? hub : hbb;
    const u16* featB = dir ? hbb : hub;
    const int* idxA = dir ? src : dst;
    const int* idxB = dir ? dst : src;
    const u16* eF = dir ? eb : eu;
    __half* out = dir ? cu : cb;

    float b1v[4], b2v[4];
#pragma unroll
    for (int n = 0; n < 4; ++n) { b1v[n] = b1[lr + 16 * n]; b2v[n] = b2[lr + 16 * n]; }

    const int rb = t * 128 + wv * 16;
    int ar = rb + lr; if (ar >= E_) ar = E_ - 1;
    const int ia = idxA[ar], ib = idxB[ar];
    bf16x8 aseq[6];
    aseq[0] = *(const bf16x8*)&featA[(size_t)ia * 64 + lk * 8];
    aseq[1] = *(const bf16x8*)&featA[(size_t)ia * 64 + 32 + lk * 8];
    aseq[2] = *(const bf16x8*)&featB[(size_t)ib * 64 + lk * 8];
    aseq[3] = *(const bf16x8*)&featB[(size_t)ib * 64 + 32 + lk * 8];
    aseq[4] = *(const bf16x8*)&eF[(size_t)ar * 64 + lk * 8];
    aseq[5] = *(const bf16x8*)&eF[(size_t)ar * 64 + 32 + lk * 8];
    f32x4 acc[4];
#pragma unroll
    for (int n = 0; n < 4; ++n) acc[n] = (f32x4){b1v[n], b1v[n], b1v[n], b1v[n]};
#pragma unroll
    for (int ks = 0; ks < 6; ++ks) {
#pragma unroll
        for (int n = 0; n < 4; ++n) {
            // W1 row (lr+16n), k-slice ks: from global (24 KB, L1-resident)
            bf16x8 bfr = *(const bf16x8*)&W1[(size_t)(lr + 16 * n) * 192 + ks * 32 + lk * 8];
            acc[n] = __builtin_amdgcn_mfma_f32_16x16x32_bf16(aseq[ks], bfr, acc[n], 0, 0, 0);
        }
    }
#pragma unroll
    for (int n = 0; n < 4; ++n)
#pragma unroll
        for (int i = 0; i < 4; ++i)
            sHid[(wv * 16 + lk * 4 + i) * 72 + lr + 16 * n] = f2bf(fmaxf(acc[n][i], 0.f));
    __syncthreads();
    f32x4 a2[4];
#pragma unroll
    for (int n = 0; n < 4; ++n) a2[n] = (f32x4){b2v[n], b2v[n], b2v[n], b2v[n]};
#pragma unroll
    for (int ks = 0; ks < 2; ++ks) {
        bf16x8 af = *(const bf16x8*)&sHid[(wv * 16 + lr) * 72 + ks * 32 + lk * 8];
#pragma unroll
        for (int n = 0; n < 4; ++n) {
            bf16x8 bfr = *(const bf16x8*)&W2[(size_t)(lr + 16 * n) * 64 + ks * 32 + lk * 8];
            a2[n] = __builtin_amdgcn_mfma_f32_16x16x32_bf16(af, bfr, a2[n], 0, 0, 0);
        }
    }
    // ---- pair even/odd channels across lane pairs; 8 half2 atomics/lane ----
    const bool odd = (lr & 1) != 0;
    float lov[4][2], hiv[4][2];
#pragma unroll
    for (int n = 0; n < 4; ++n) {
        float o0 = __shfl_xor(a2[n][0], 1);
        float o1 = __shfl_xor(a2[n][1], 1);
        float o2 = __shfl_xor(a2[n][2], 1);
        float o3 = __shfl_xor(a2[n][3], 1);
        lov[n][0] = odd ? o2 : a2[n][0];
        hiv[n][0] = odd ? a2[n][2] : o0;
        lov[n][1] = odd ? o3 : a2[n][1];
        hiv[n][1] = odd ? a2[n][3] : o1;
    }
    const int ibase = odd ? 2 : 0;
    const int cpair = lr & ~1;
#pragma unroll
    for (int k = 0; k < 2; ++k) {
        int r = rb + lk * 4 + ibase + k;
        if (r < E_) {
            const int o = idxA[r];
            __half* bp = out + (size_t)o * 64 + cpair;
#pragma unroll
            for (int n = 0; n < 4; ++n)
                unsafeAtomicAdd((__half2*)(bp + 16 * n),
                                __floats2half2_rn(lov[n][k], hiv[n][k]));
        }
    }
}

// ------- update on bf16 h-state; optionally re-zeroes conv ------------------
__global__ void update_kernel(u16* __restrict__ hbf, __half2* __restrict__ c2,
                              int n4, int relu_res, int zero_next)
{
    const int st = gridDim.x * blockDim.x;
    const __half2 hz = __floats2half2_rn(0.f, 0.f);
    for (int j = blockIdx.x * blockDim.x + threadIdx.x; j < n4; j += st) {
        u16x4 hp = ((const u16x4*)hbf)[j];
        float2 f0 = __half22float2(c2[2 * j]);
        float2 f1 = __half22float2(c2[2 * j + 1]);
        if (zero_next) { c2[2 * j] = hz; c2[2 * j + 1] = hz; }
        float v0, v1, v2, v3;
        if (relu_res) {
            v0 = fmaxf(fmaf(bf2f(hp[0]), 2.1f, f0.x), 0.f);
            v1 = fmaxf(fmaf(bf2f(hp[1]), 2.1f, f0.y), 0.f);
            v2 = fmaxf(fmaf(bf2f(hp[2]), 2.1f, f1.x), 0.f);
            v3 = fmaxf(fmaf(bf2f(hp[3]), 2.1f, f1.y), 0.f);
        } else {
            v0 = fmaf(bf2f(hp[0]), 1.1f, f0.x);
            v1 = fmaf(bf2f(hp[1]), 1.1f, f0.y);
            v2 = fmaf(bf2f(hp[2]), 1.1f, f1.x);
            v3 = fmaf(bf2f(hp[3]), 1.1f, f1.y);
        }
        u16x4 p;
        p[0] = f2bf(v0); p[1] = f2bf(v1); p[2] = f2bf(v2); p[3] = f2bf(v3);
        ((u16x4*)hbf)[j] = p;
    }
}

// ---------------- classifier ------------------------------------------------
__global__ __launch_bounds__(512) void cls_mfma(
    const u16* __restrict__ hub, const u16* __restrict__ hbb,
    const int* __restrict__ i0, const int* __restrict__ i1, int EL_,
    const u16* __restrict__ W1, const float* __restrict__ b1,
    const float* __restrict__ W2, const float* __restrict__ b2,
    float* __restrict__ out)
{
    __shared__ u16 sW1[64 * 136];
    const int tid = threadIdx.x;
    const int wv = tid >> 6, lane = tid & 63;
    const int lr = lane & 15, lk = lane >> 4;
    for (int c = tid; c < 1024; c += 512) {
        int row = c >> 4, cc = c & 15;
        *(bf16x8*)&sW1[row * 136 + cc * 8] = *(const bf16x8*)&W1[row * 128 + cc * 8];
    }
    float b1v[4], w2v[4];
#pragma unroll
    for (int n = 0; n < 4; ++n) { b1v[n] = b1[lr + 16 * n]; w2v[n] = W2[lr + 16 * n]; }
    const float b2s = b2[0];
    __syncthreads();

    const int nT = (EL_ + 127) >> 7;
    for (int t = blockIdx.x; t < nT; t += gridDim.x) {
        const int rb = t * 128 + wv * 16;
        int ar = rb + lr; if (ar >= EL_) ar = EL_ - 1;
        const int gu = i0[ar], gb = i1[ar];
        bf16x8 af[4];
        af[0] = *(const bf16x8*)&hub[(size_t)gu * 64 + lk * 8];
        af[1] = *(const bf16x8*)&hub[(size_t)gu * 64 + 32 + lk * 8];
        af[2] = *(const bf16x8*)&hbb[(size_t)gb * 64 + lk * 8];
        af[3] = *(const bf16x8*)&hbb[(size_t)gb * 64 + 32 + lk * 8];
        f32x4 acc[4];
#pragma unroll
        for (int n = 0; n < 4; ++n) acc[n] = (f32x4){b1v[n], b1v[n], b1v[n], b1v[n]};
#pragma unroll
        for (int ks = 0; ks < 4; ++ks) {
#pragma unroll
            for (int n = 0; n < 4; ++n) {
                bf16x8 bfr = *(const bf16x8*)&sW1[(lr + 16 * n) * 136 + ks * 32 + lk * 8];
                acc[n] = __builtin_amdgcn_mfma_f32_16x16x32_bf16(af[ks], bfr, acc[n], 0, 0, 0);
            }
        }
#pragma unroll
        for (int i = 0; i < 4; ++i) {
            float v = 0.f;
#pragma unroll
            for (int n = 0; n < 4; ++n) v = fmaf(fmaxf(acc[n][i], 0.f), w2v[n], v);
            v += __shfl_xor(v, 1); v += __shfl_xor(v, 2);
            v += __shfl_xor(v, 4); v += __shfl_xor(v, 8);
            int r = rb + lk * 4 + i;
            if (lr == 0 && r < EL_) out[r] = v + b2s;
        }
    }
}

extern "C" void kernel_launch(void* const* d_in, const int* in_sizes, int n_in,
                              void* d_out, int out_size, void* d_ws, size_t ws_size,
                              hipStream_t stream)
{
    const float* emb_user = (const float*)d_in[0];
    const float* emb_book = (const float*)d_in[1];
    const float* nu_W1 = (const float*)d_in[2];
    const float* nu_b1 = (const float*)d_in[3];
    const float* nu_W2 = (const float*)d_in[4];
    const float* nu_b2 = (const float*)d_in[5];
    const float* nb_W1 = (const float*)d_in[6];
    const float* nb_b1 = (const float*)d_in[7];
    const float* nb_W2 = (const float*)d_in[8];
    const float* nb_b2 = (const float*)d_in[9];
    const float* eu_W1 = (const float*)d_in[10];
    const float* eu_b1 = (const float*)d_in[11];
    const float* eu_W2 = (const float*)d_in[12];
    const float* eu_b2 = (const float*)d_in[13];
    const float* eb_W1 = (const float*)d_in[14];
    const float* eb_b1 = (const float*)d_in[15];
    const float* eb_W2 = (const float*)d_in[16];
    const float* eb_b2 = (const float*)d_in[17];
    const float* cu2b_W1 = (const float*)d_in[18];
    const float* cu2b_b1 = (const float*)d_in[19];
    const float* cu2b_W2 = (const float*)d_in[20];
    const float* cu2b_b2 = (const float*)d_in[21];
    const float* cb2u_W1 = (const float*)d_in[22];
    const float* cb2u_b1 = (const float*)d_in[23];
    const float* cb2u_W2 = (const float*)d_in[24];
    const float* cb2u_b2 = (const float*)d_in[25];
    const float* cls_W1 = (const float*)d_in[26];
    const float* cls_b1 = (const float*)d_in[27];
    const float* cls_W2 = (const float*)d_in[28];
    const float* cls_b2 = (const float*)d_in[29];
    const float* edge_attr = (const float*)d_in[30];
    const int* n_id_user = (const int*)d_in[31];
    const int* n_id_book = (const int*)d_in[32];
    const int* edge_index = (const int*)d_in[33];
    const int* edge_label_index = (const int*)d_in[34];

    const int NU = in_sizes[31];
    const int NB = in_sizes[32];
    const int E  = in_sizes[33] / 2;
    const int EL = in_sizes[34] / 2;

    const int* src = edge_index;
    const int* dst = edge_index + E;
    const int* li0 = edge_label_index;
    const int* li1 = edge_label_index + EL;

    // workspace layout (no f32 h state)
    __half* cuh = (__half*)d_ws;                       // NU*64 f16
    __half* cbh = cuh + (size_t)NU * 64;               // NB*64 f16
    u16* hu_b = (u16*)(cbh + (size_t)NB * 64);         // NU*64 bf16
    u16* hb_b = hu_b + (size_t)NU * 64;                // NB*64 bf16
    u16* eu_b = hb_b + (size_t)NB * 64;                // E*64 bf16
    u16* eb_b = eu_b + (size_t)E * 64;                 // E*64 bf16
    u16* pool = eb_b + (size_t)E * 64;

    // ---- weight prep ----
    PrepArgs pa;
    const float* srcs[NMAT] = { nu_W1, nu_W2, nb_W1, nb_W2, eu_W1, eu_W2, eb_W1, eb_W2,
        cu2b_W1, cu2b_W1 + 192 * 64, cu2b_W2, cu2b_W2 + 64 * 64,
        cb2u_W1, cb2u_W1 + 192 * 64, cb2u_W2, cb2u_W2 + 64 * 64, cls_W1 };
    const int Ks[NMAT] = {64,64,64,64, 256,64,256,64, 192,192,64,64, 192,192,64,64, 128};
    int offs[NMAT]; int off = 0;
    for (int m = 0; m < NMAT; ++m) { offs[m] = off; off += Ks[m] * 64; }
    for (int m = 0; m < NMAT; ++m) { pa.src[m] = srcs[m]; pa.dstoff[m] = offs[m]; pa.K[m] = Ks[m]; }
    prep_weights<<<NMAT * 64, 256, 0, stream>>>(pa, pool);

    const u16* p_nuW1 = pool + offs[0]; const u16* p_nuW2 = pool + offs[1];
    const u16* p_nbW1 = pool + offs[2]; const u16* p_nbW2 = pool + offs[3];
    const u16* p_euW1 = pool + offs[4]; const u16* p_euW2 = pool + offs[5];
    const u16* p_ebW1 = pool + offs[6]; const u16* p_ebW2 = pool + offs[7];
    const u16* p_u2bW1[2] = { pool + offs[8],  pool + offs[9]  };
    const u16* p_u2bW2[2] = { pool + offs[10], pool + offs[11] };
    const u16* p_b2uW1[2] = { pool + offs[12], pool + offs[13] };
    const u16* p_b2uW2[2] = { pool + offs[14], pool + offs[15] };
    const u16* p_clsW1 = pool + offs[16];

    // ---- node + edge init (node_init also zeroes conv accumulators) ----
    const int nTu = (NU + 127) / 128, nTb = (NB + 127) / 128;
    node_init_both<<<nTu + nTb, 512, 0, stream>>>(
        emb_user, n_id_user, NU, emb_book, n_id_book, NB, nTu,
        p_nuW1, nu_b1, p_nuW2, nu_b2, p_nbW1, nb_b1, p_nbW2, nb_b2,
        hu_b, cuh);
    edge_init_fused<<<(E + 127) / 128, 512, 0, stream>>>(edge_attr, E,
        p_euW1, eu_b1, p_euW2, eu_b2, p_ebW1, eb_b1, p_ebW2, eb_b2, eu_b, eb_b);

    const int n4 = (NU + NB) * 16;          // u16x4 groups of bf16 h
    const int nTe = (E + 127) / 128;
    const int gMsg = ((nTe + 7) / 8) * 16;  // XCD-paired swizzle grid
    // ---- conv layers ----
    for (int l = 0; l < 2; ++l) {
        edge_msg_both<<<gMsg, 512, 0, stream>>>(hu_b, hb_b, src, dst,
            eu_b, eb_b, E,
            p_u2bW1[l], cu2b_b1 + l * 64, p_u2bW2[l], cu2b_b2 + l * 64,
            p_b2uW1[l], cb2u_b1 + l * 64, p_b2uW2[l], cb2u_b2 + l * 64,
            cbh, cuh);
        update_kernel<<<1024, 256, 0, stream>>>(hu_b, (__half2*)cuh, n4,
            l == 0 ? 1 : 0, l == 0 ? 1 : 0);
    }

    // ---- classifier ----
    cls_mfma<<<(EL + 127) / 128, 512, 0, stream>>>(hu_b, hb_b, li0, li1, EL,
        p_clsW1, cls_b1, cls_W2, cls_b2, (float*)d_out);
}

// Round 21
// 480.837 us; speedup vs baseline: 1.2495x; 1.2495x over previous
//
#include <hip/hip_runtime.h>
#include <hip/hip_fp16.h>

typedef unsigned short u16;
typedef __attribute__((ext_vector_type(8))) short bf16x8;
typedef __attribute__((ext_vector_type(4))) float f32x4;
typedef __attribute__((ext_vector_type(4))) unsigned short u16x4;

#define NMAT 17

__device__ __forceinline__ u16 f2bf(float f) {
    union { float f; unsigned u; } a; a.f = f;
    unsigned u = a.u;
    return (u16)((u + (((u >> 16) & 1u) + 0x7fffu)) >> 16);
}
__device__ __forceinline__ float bf2f(u16 v) {
    union { unsigned u; float f; } a; a.u = ((unsigned)v) << 16;
    return a.f;
}

// ---------------- weight prep: W[K][64] f32 -> Wt[64][K] bf16 ----------------
struct PrepArgs { const float* src[NMAT]; int dstoff[NMAT]; int K[NMAT]; };

__global__ __launch_bounds__(256) void prep_weights(PrepArgs a, u16* __restrict__ pool) {
    int m = blockIdx.x >> 6;
    int idx = (blockIdx.x & 63) * 256 + threadIdx.x;
    int K = a.K[m];
    if (idx < K * 64) {
        int col = idx / K, k = idx - col * K;
        pool[a.dstoff[m] + idx] = f2bf(a.src[m][(size_t)k * 64 + col]);
    }
}

// ------- node init, BOTH tables; also zero-inits the conv accumulator -------
__global__ __launch_bounds__(512) void node_init_both(
    const float* __restrict__ emb_u, const int* __restrict__ nid_u, int NU_,
    const float* __restrict__ emb_b, const int* __restrict__ nid_b, int NB_, int nTu,
    const u16* __restrict__ W1u, const float* __restrict__ b1u,
    const u16* __restrict__ W2u, const float* __restrict__ b2u,
    const u16* __restrict__ W1b, const float* __restrict__ b1b,
    const u16* __restrict__ W2b, const float* __restrict__ b2b,
    u16* __restrict__ hbf, __half* __restrict__ conv)
{
    __shared__ u16 sW1[64 * 72], sW2[64 * 72], sHid[128 * 72];
    const int tid = threadIdx.x;
    const int wv = tid >> 6, lane = tid & 63;
    const int lr = lane & 15, lk = lane >> 4;

    int t = blockIdx.x;
    const bool isB = t >= nTu;
    if (isB) t -= nTu;
    const int N = isB ? NB_ : NU_;
    const int rowoff = isB ? NU_ : 0;
    const float* emb = isB ? emb_b : emb_u;
    const int* nid = isB ? nid_b : nid_u;
    const u16* W1 = isB ? W1b : W1u;
    const u16* W2 = isB ? W2b : W2u;
    const float* b1 = isB ? b1b : b1u;
    const float* b2 = isB ? b2b : b2u;

    for (int c = tid; c < 512; c += 512) {
        int row = c >> 3, cc = c & 7;
        *(bf16x8*)&sW1[row * 72 + cc * 8] = *(const bf16x8*)&W1[row * 64 + cc * 8];
        *(bf16x8*)&sW2[row * 72 + cc * 8] = *(const bf16x8*)&W2[row * 64 + cc * 8];
    }
    // zero conv rows for this tile
    const int rb0 = t * 128;
    const f32x4 zv = (f32x4){0.f, 0.f, 0.f, 0.f};
#pragma unroll
    for (int c = tid; c < 1024; c += 512) {
        int row = rb0 + (c >> 3), cc = c & 7;
        if (row < N)
            ((f32x4*)&conv[(size_t)(rowoff + row) * 64])[cc] = zv;
    }
    float b1v[4], b2v[4];
#pragma unroll
    for (int n = 0; n < 4; ++n) { b1v[n] = b1[lr + 16 * n]; b2v[n] = b2[lr + 16 * n]; }

    const int rb = t * 128 + wv * 16;
    int ar = rb + lr; if (ar >= N) ar = N - 1;
    const int g = nid[ar];
    const float* ap = emb + (size_t)g * 64 + lk * 8;
    bf16x8 afr[2];
#pragma unroll
    for (int ks = 0; ks < 2; ++ks) {
        f32x4 lo = *(const f32x4*)(ap + ks * 32);
        f32x4 hi = *(const f32x4*)(ap + ks * 32 + 4);
        bf16x8 v;
        v[0] = (short)f2bf(lo[0]); v[1] = (short)f2bf(lo[1]);
        v[2] = (short)f2bf(lo[2]); v[3] = (short)f2bf(lo[3]);
        v[4] = (short)f2bf(hi[0]); v[5] = (short)f2bf(hi[1]);
        v[6] = (short)f2bf(hi[2]); v[7] = (short)f2bf(hi[3]);
        afr[ks] = v;
    }
    __syncthreads();
    f32x4 acc[4];
#pragma unroll
    for (int n = 0; n < 4; ++n) acc[n] = (f32x4){b1v[n], b1v[n], b1v[n], b1v[n]};
#pragma unroll
    for (int ks = 0; ks < 2; ++ks) {
#pragma unroll
        for (int n = 0; n < 4; ++n) {
            bf16x8 bfr = *(const bf16x8*)&sW1[(lr + 16 * n) * 72 + ks * 32 + lk * 8];
            acc[n] = __builtin_amdgcn_mfma_f32_16x16x32_bf16(afr[ks], bfr, acc[n], 0, 0, 0);
        }
    }
#pragma unroll
    for (int n = 0; n < 4; ++n)
#pragma unroll
        for (int i = 0; i < 4; ++i)
            sHid[(wv * 16 + lk * 4 + i) * 72 + lr + 16 * n] = f2bf(fmaxf(acc[n][i], 0.f));
    __syncthreads();
    f32x4 a2[4];
#pragma unroll
    for (int n = 0; n < 4; ++n) a2[n] = (f32x4){b2v[n], b2v[n], b2v[n], b2v[n]};
#pragma unroll
    for (int ks = 0; ks < 2; ++ks) {
        bf16x8 af = *(const bf16x8*)&sHid[(wv * 16 + lr) * 72 + ks * 32 + lk * 8];
#pragma unroll
        for (int n = 0; n < 4; ++n) {
            bf16x8 bfr = *(const bf16x8*)&sW2[(lr + 16 * n) * 72 + ks * 32 + lk * 8];
            a2[n] = __builtin_amdgcn_mfma_f32_16x16x32_bf16(af, bfr, a2[n], 0, 0, 0);
        }
    }
#pragma unroll
    for (int i = 0; i < 4; ++i) {
        int r = rb + lk * 4 + i;
        if (r < N) {
            size_t gr = (size_t)(rowoff + r);
#pragma unroll
            for (int n = 0; n < 4; ++n)
                hbf[gr * 64 + lr + 16 * n] = f2bf(a2[n][i]);
        }
    }
}

// -------- fused edge init: persistent weights, double-buffered sHid ---------
__global__ __launch_bounds__(512) void edge_init_fused(
    const float* __restrict__ attr, int E_,
    const u16* __restrict__ W1u, const float* __restrict__ b1u,
    const u16* __restrict__ W2u, const float* __restrict__ b2u,
    const u16* __restrict__ W1b, const float* __restrict__ b1b,
    const u16* __restrict__ W2b, const float* __restrict__ b2b,
    u16* __restrict__ eu, u16* __restrict__ eb)
{
    __shared__ u16 sW1[2][64 * 264];
    __shared__ u16 sW2[2][64 * 72];
    __shared__ u16 sHid[2][128 * 72];
    const int tid = threadIdx.x;
    const int wv = tid >> 6, lane = tid & 63;
    const int lr = lane & 15, lk = lane >> 4;

    for (int c = tid; c < 4096; c += 512) {
        int d = c >> 11, rem = c & 2047;
        int row = rem >> 5, cc = rem & 31;
        const u16* w = d ? W1b : W1u;
        *(bf16x8*)&sW1[d][row * 264 + cc * 8] = *(const bf16x8*)&w[row * 256 + cc * 8];
    }
    for (int c = tid; c < 1024; c += 512) {
        int d = c >> 9, rem = c & 511;
        int row = rem >> 3, cc = rem & 7;
        const u16* w = d ? W2b : W2u;
        *(bf16x8*)&sW2[d][row * 72 + cc * 8] = *(const bf16x8*)&w[row * 64 + cc * 8];
    }
    float b1v[2][4], b2v[2][4];
#pragma unroll
    for (int n = 0; n < 4; ++n) {
        b1v[0][n] = b1u[lr + 16 * n]; b1v[1][n] = b1b[lr + 16 * n];
        b2v[0][n] = b2u[lr + 16 * n]; b2v[1][n] = b2b[lr + 16 * n];
    }
    __syncthreads();

    const int nT = (E_ + 127) >> 7;
    for (int t = blockIdx.x; t < nT; t += gridDim.x) {
        const int rb = t * 128 + wv * 16;
        int ar = rb + lr; if (ar >= E_) ar = E_ - 1;
        const float* ap = attr + (size_t)ar * 256 + lk * 8;
        bf16x8 afr[8];
#pragma unroll
        for (int ks = 0; ks < 8; ++ks) {
            f32x4 lo = *(const f32x4*)(ap + ks * 32);
            f32x4 hi = *(const f32x4*)(ap + ks * 32 + 4);
            bf16x8 v;
            v[0] = (short)f2bf(lo[0]); v[1] = (short)f2bf(lo[1]);
            v[2] = (short)f2bf(lo[2]); v[3] = (short)f2bf(lo[3]);
            v[4] = (short)f2bf(hi[0]); v[5] = (short)f2bf(hi[1]);
            v[6] = (short)f2bf(hi[2]); v[7] = (short)f2bf(hi[3]);
            afr[ks] = v;
        }
#pragma unroll
        for (int dir = 0; dir < 2; ++dir) {
            f32x4 acc[4];
#pragma unroll
            for (int n = 0; n < 4; ++n) acc[n] = (f32x4){b1v[dir][n], b1v[dir][n], b1v[dir][n], b1v[dir][n]};
#pragma unroll
            for (int ks = 0; ks < 8; ++ks) {
#pragma unroll
                for (int n = 0; n < 4; ++n) {
                    bf16x8 bfr = *(const bf16x8*)&sW1[dir][(lr + 16 * n) * 264 + ks * 32 + lk * 8];
                    acc[n] = __builtin_amdgcn_mfma_f32_16x16x32_bf16(afr[ks], bfr, acc[n], 0, 0, 0);
                }
            }
#pragma unroll
            for (int n = 0; n < 4; ++n)
#pragma unroll
                for (int i = 0; i < 4; ++i)
                    sHid[dir][(wv * 16 + lk * 4 + i) * 72 + lr + 16 * n] = f2bf(fmaxf(acc[n][i], 0.f));
            __syncthreads();
            f32x4 a2[4];
#pragma unroll
            for (int n = 0; n < 4; ++n) a2[n] = (f32x4){b2v[dir][n], b2v[dir][n], b2v[dir][n], b2v[dir][n]};
#pragma unroll
            for (int ks = 0; ks < 2; ++ks) {
                bf16x8 af = *(const bf16x8*)&sHid[dir][(wv * 16 + lr) * 72 + ks * 32 + lk * 8];
#pragma unroll
                for (int n = 0; n < 4; ++n) {
                    bf16x8 bfr = *(const bf16x8*)&sW2[dir][(lr + 16 * n) * 72 + ks * 32 + lk * 8];
                    a2[n] = __builtin_amdgcn_mfma_f32_16x16x32_bf16(af, bfr, a2[n], 0, 0, 0);
                }
            }
            u16* op = dir ? eb : eu;
#pragma unroll
            for (int i = 0; i < 4; ++i) {
                int r = rb + lk * 4 + i;
                if (r < E_) {
#pragma unroll
                    for (int n = 0; n < 4; ++n)
                        op[(size_t)r * 64 + lr + 16 * n] = f2bf(a2[n][i]);
                }
            }
        }
    }
}

// -------- edge messages: LDS weights staged ONCE per block, 4 tiles/block ---
// dir = blockIdx&1; tile group = blockIdx>>1 covers tiles [g*4, g*4+4).
// Weight staging amortized 4x vs 1-tile blocks; barriers: 1 + 2/tile.
#define MSG_NITER 4
__global__ __launch_bounds__(512) void edge_msg_both(
    const u16* __restrict__ hub, const u16* __restrict__ hbb,
    const int* __restrict__ src, const int* __restrict__ dst,
    const u16* __restrict__ eu, const u16* __restrict__ eb, int E_,
    const u16* __restrict__ W1a, const float* __restrict__ b1a,
    const u16* __restrict__ W2a, const float* __restrict__ b2a,
    const u16* __restrict__ W1b, const float* __restrict__ b1b,
    const u16* __restrict__ W2b, const float* __restrict__ b2b,
    __half* __restrict__ cb, __half* __restrict__ cu)
{
    __shared__ u16 sW1[64 * 200];
    __shared__ u16 sW2[64 * 72];
    __shared__ u16 sHid[128 * 72];
    const int tid = threadIdx.x;
    const int wv = tid >> 6, lane = tid & 63;
    const int lr = lane & 15, lk = lane >> 4;

    const int nTe = (E_ + 127) >> 7;
    const int dir = blockIdx.x & 1;
    const int g = blockIdx.x >> 1;

    const u16* W1 = dir ? W1b : W1a;
    const u16* W2 = dir ? W2b : W2a;
    const float* b1 = dir ? b1b : b1a;
    const float* b2 = dir ? b2b : b2a;
    const u16* featA = dir ? hub : hbb;
    const u16* featB = dir ? hbb : hub;
    const int* idxA = dir ? src : dst;
    const int* idxB = dir ? dst : src;
    const u16* eF = dir ? eb : eu;
    __half* out = dir ? cu : cb;

    for (int c = tid; c < 1536; c += 512) {
        int row = c / 24, cc = c - row * 24;
        *(bf16x8*)&sW1[row * 200 + cc * 8] = *(const bf16x8*)&W1[row * 192 + cc * 8];
    }
    for (int c = tid; c < 512; c += 512) {
        int row = c >> 3, cc = c & 7;
        *(bf16x8*)&sW2[row * 72 + cc * 8] = *(const bf16x8*)&W2[row * 64 + cc * 8];
    }
    float b1v[4], b2v[4];
#pragma unroll
    for (int n = 0; n < 4; ++n) { b1v[n] = b1[lr + 16 * n]; b2v[n] = b2[lr + 16 * n]; }
    __syncthreads();   // weights staged (once per block)

    for (int tt = 0; tt < MSG_NITER; ++tt) {
        const int t = g * MSG_NITER + tt;   // uniform across block -> uniform break
        if (t >= nTe) break;
        const int rb = t * 128 + wv * 16;
        int ar = rb + lr; if (ar >= E_) ar = E_ - 1;
        const int ia = idxA[ar], ib = idxB[ar];
        bf16x8 aseq[6];
        aseq[0] = *(const bf16x8*)&featA[(size_t)ia * 64 + lk * 8];
        aseq[1] = *(const bf16x8*)&featA[(size_t)ia * 64 + 32 + lk * 8];
        aseq[2] = *(const bf16x8*)&featB[(size_t)ib * 64 + lk * 8];
        aseq[3] = *(const bf16x8*)&featB[(size_t)ib * 64 + 32 + lk * 8];
        aseq[4] = *(const bf16x8*)&eF[(size_t)ar * 64 + lk * 8];
        aseq[5] = *(const bf16x8*)&eF[(size_t)ar * 64 + 32 + lk * 8];
        f32x4 acc[4];
#pragma unroll
        for (int n = 0; n < 4; ++n) acc[n] = (f32x4){b1v[n], b1v[n], b1v[n], b1v[n]};
#pragma unroll
        for (int ks = 0; ks < 6; ++ks) {
#pragma unroll
            for (int n = 0; n < 4; ++n) {
                bf16x8 bfr = *(const bf16x8*)&sW1[(lr + 16 * n) * 200 + ks * 32 + lk * 8];
                acc[n] = __builtin_amdgcn_mfma_f32_16x16x32_bf16(aseq[ks], bfr, acc[n], 0, 0, 0);
            }
        }
        __syncthreads();   // prev tile's sHid reads complete
#pragma unroll
        for (int n = 0; n < 4; ++n)
#pragma unroll
            for (int i = 0; i < 4; ++i)
                sHid[(wv * 16 + lk * 4 + i) * 72 + lr + 16 * n] = f2bf(fmaxf(acc[n][i], 0.f));
        __syncthreads();   // sHid published
        f32x4 a2[4];
#pragma unroll
        for (int n = 0; n < 4; ++n) a2[n] = (f32x4){b2v[n], b2v[n], b2v[n], b2v[n]};
#pragma unroll
        for (int ks = 0; ks < 2; ++ks) {
            bf16x8 af = *(const bf16x8*)&sHid[(wv * 16 + lr) * 72 + ks * 32 + lk * 8];
#pragma unroll
            for (int n = 0; n < 4; ++n) {
                bf16x8 bfr = *(const bf16x8*)&sW2[(lr + 16 * n) * 72 + ks * 32 + lk * 8];
                a2[n] = __builtin_amdgcn_mfma_f32_16x16x32_bf16(af, bfr, a2[n], 0, 0, 0);
            }
        }
        // ---- pair even/odd channels across lane pairs; 8 half2 atomics/lane ----
        const bool odd = (lr & 1) != 0;
        float lov[4][2], hiv[4][2];
#pragma unroll
        for (int n = 0; n < 4; ++n) {
            float o0 = __shfl_xor(a2[n][0], 1);
            float o1 = __shfl_xor(a2[n][1], 1);
            float o2 = __shfl_xor(a2[n][2], 1);
            float o3 = __shfl_xor(a2[n][3], 1);
            lov[n][0] = odd ? o2 : a2[n][0];
            hiv[n][0] = odd ? a2[n][2] : o0;
            lov[n][1] = odd ? o3 : a2[n][1];
            hiv[n][1] = odd ? a2[n][3] : o1;
        }
        const int ibase = odd ? 2 : 0;
        const int cpair = lr & ~1;
#pragma unroll
        for (int k = 0; k < 2; ++k) {
            int r = rb + lk * 4 + ibase + k;
            if (r < E_) {
                const int o = idxA[r];
                __half* bp = out + (size_t)o * 64 + cpair;
#pragma unroll
                for (int n = 0; n < 4; ++n)
                    unsafeAtomicAdd((__half2*)(bp + 16 * n),
                                    __floats2half2_rn(lov[n][k], hiv[n][k]));
            }
        }
    }
}

// ------- update on bf16 h-state; optionally re-zeroes conv ------------------
__global__ void update_kernel(u16* __restrict__ hbf, __half2* __restrict__ c2,
                              int n4, int relu_res, int zero_next)
{
    const int st = gridDim.x * blockDim.x;
    const __half2 hz = __floats2half2_rn(0.f, 0.f);
    for (int j = blockIdx.x * blockDim.x + threadIdx.x; j < n4; j += st) {
        u16x4 hp = ((const u16x4*)hbf)[j];
        float2 f0 = __half22float2(c2[2 * j]);
        float2 f1 = __half22float2(c2[2 * j + 1]);
        if (zero_next) { c2[2 * j] = hz; c2[2 * j + 1] = hz; }
        float v0, v1, v2, v3;
        if (relu_res) {
            v0 = fmaxf(fmaf(bf2f(hp[0]), 2.1f, f0.x), 0.f);
            v1 = fmaxf(fmaf(bf2f(hp[1]), 2.1f, f0.y), 0.f);
            v2 = fmaxf(fmaf(bf2f(hp[2]), 2.1f, f1.x), 0.f);
            v3 = fmaxf(fmaf(bf2f(hp[3]), 2.1f, f1.y), 0.f);
        } else {
            v0 = fmaf(bf2f(hp[0]), 1.1f, f0.x);
            v1 = fmaf(bf2f(hp[1]), 1.1f, f0.y);
            v2 = fmaf(bf2f(hp[2]), 1.1f, f1.x);
            v3 = fmaf(bf2f(hp[3]), 1.1f, f1.y);
        }
        u16x4 p;
        p[0] = f2bf(v0); p[1] = f2bf(v1); p[2] = f2bf(v2); p[3] = f2bf(v3);
        ((u16x4*)hbf)[j] = p;
    }
}

// ---------------- classifier ------------------------------------------------
__global__ __launch_bounds__(512) void cls_mfma(
    const u16* __restrict__ hub, const u16* __restrict__ hbb,
    const int* __restrict__ i0, const int* __restrict__ i1, int EL_,
    const u16* __restrict__ W1, const float* __restrict__ b1,
    const float* __restrict__ W2, const float* __restrict__ b2,
    float* __restrict__ out)
{
    __shared__ u16 sW1[64 * 136];
    const int tid = threadIdx.x;
    const int wv = tid >> 6, lane = tid & 63;
    const int lr = lane & 15, lk = lane >> 4;
    for (int c = tid; c < 1024; c += 512) {
        int row = c >> 4, cc = c & 15;
        *(bf16x8*)&sW1[row * 136 + cc * 8] = *(const bf16x8*)&W1[row * 128 + cc * 8];
    }
    float b1v[4], w2v[4];
#pragma unroll
    for (int n = 0; n < 4; ++n) { b1v[n] = b1[lr + 16 * n]; w2v[n] = W2[lr + 16 * n]; }
    const float b2s = b2[0];
    __syncthreads();

    const int nT = (EL_ + 127) >> 7;
    for (int t = blockIdx.x; t < nT; t += gridDim.x) {
        const int rb = t * 128 + wv * 16;
        int ar = rb + lr; if (ar >= EL_) ar = EL_ - 1;
        const int gu = i0[ar], gb = i1[ar];
        bf16x8 af[4];
        af[0] = *(const bf16x8*)&hub[(size_t)gu * 64 + lk * 8];
        af[1] = *(const bf16x8*)&hub[(size_t)gu * 64 + 32 + lk * 8];
        af[2] = *(const bf16x8*)&hbb[(size_t)gb * 64 + lk * 8];
        af[3] = *(const bf16x8*)&hbb[(size_t)gb * 64 + 32 + lk * 8];
        f32x4 acc[4];
#pragma unroll
        for (int n = 0; n < 4; ++n) acc[n] = (f32x4){b1v[n], b1v[n], b1v[n], b1v[n]};
#pragma unroll
        for (int ks = 0; ks < 4; ++ks) {
#pragma unroll
            for (int n = 0; n < 4; ++n) {
                bf16x8 bfr = *(const bf16x8*)&sW1[(lr + 16 * n) * 136 + ks * 32 + lk * 8];
                acc[n] = __builtin_amdgcn_mfma_f32_16x16x32_bf16(af[ks], bfr, acc[n], 0, 0, 0);
            }
        }
#pragma unroll
        for (int i = 0; i < 4; ++i) {
            float v = 0.f;
#pragma unroll
            for (int n = 0; n < 4; ++n) v = fmaf(fmaxf(acc[n][i], 0.f), w2v[n], v);
            v += __shfl_xor(v, 1); v += __shfl_xor(v, 2);
            v += __shfl_xor(v, 4); v += __shfl_xor(v, 8);
            int r = rb + lk * 4 + i;
            if (lr == 0 && r < EL_) out[r] = v + b2s;
        }
    }
}

extern "C" void kernel_launch(void* const* d_in, const int* in_sizes, int n_in,
                              void* d_out, int out_size, void* d_ws, size_t ws_size,
                              hipStream_t stream)
{
    const float* emb_user = (const float*)d_in[0];
    const float* emb_book = (const float*)d_in[1];
    const float* nu_W1 = (const float*)d_in[2];
    const float* nu_b1 = (const float*)d_in[3];
    const float* nu_W2 = (const float*)d_in[4];
    const float* nu_b2 = (const float*)d_in[5];
    const float* nb_W1 = (const float*)d_in[6];
    const float* nb_b1 = (const float*)d_in[7];
    const float* nb_W2 = (const float*)d_in[8];
    const float* nb_b2 = (const float*)d_in[9];
    const float* eu_W1 = (const float*)d_in[10];
    const float* eu_b1 = (const float*)d_in[11];
    const float* eu_W2 = (const float*)d_in[12];
    const float* eu_b2 = (const float*)d_in[13];
    const float* eb_W1 = (const float*)d_in[14];
    const float* eb_b1 = (const float*)d_in[15];
    const float* eb_W2 = (const float*)d_in[16];
    const float* eb_b2 = (const float*)d_in[17];
    const float* cu2b_W1 = (const float*)d_in[18];
    const float* cu2b_b1 = (const float*)d_in[19];
    const float* cu2b_W2 = (const float*)d_in[20];
    const float* cu2b_b2 = (const float*)d_in[21];
    const float* cb2u_W1 = (const float*)d_in[22];
    const float* cb2u_b1 = (const float*)d_in[23];
    const float* cb2u_W2 = (const float*)d_in[24];
    const float* cb2u_b2 = (const float*)d_in[25];
    const float* cls_W1 = (const float*)d_in[26];
    const float* cls_b1 = (const float*)d_in[27];
    const float* cls_W2 = (const float*)d_in[28];
    const float* cls_b2 = (const float*)d_in[29];
    const float* edge_attr = (const float*)d_in[30];
    const int* n_id_user = (const int*)d_in[31];
    const int* n_id_book = (const int*)d_in[32];
    const int* edge_index = (const int*)d_in[33];
    const int* edge_label_index = (const int*)d_in[34];

    const int NU = in_sizes[31];
    const int NB = in_sizes[32];
    const int E  = in_sizes[33] / 2;
    const int EL = in_sizes[34] / 2;

    const int* src = edge_index;
    const int* dst = edge_index + E;
    const int* li0 = edge_label_index;
    const int* li1 = edge_label_index + EL;

    // workspace layout (no f32 h state)
    __half* cuh = (__half*)d_ws;                       // NU*64 f16
    __half* cbh = cuh + (size_t)NU * 64;               // NB*64 f16
    u16* hu_b = (u16*)(cbh + (size_t)NB * 64);         // NU*64 bf16
    u16* hb_b = hu_b + (size_t)NU * 64;                // NB*64 bf16
    u16* eu_b = hb_b + (size_t)NB * 64;                // E*64 bf16
    u16* eb_b = eu_b + (size_t)E * 64;                 // E*64 bf16
    u16* pool = eb_b + (size_t)E * 64;

    // ---- weight prep ----
    PrepArgs pa;
    const float* srcs[NMAT] = { nu_W1, nu_W2, nb_W1, nb_W2, eu_W1, eu_W2, eb_W1, eb_W2,
        cu2b_W1, cu2b_W1 + 192 * 64, cu2b_W2, cu2b_W2 + 64 * 64,
        cb2u_W1, cb2u_W1 + 192 * 64, cb2u_W2, cb2u_W2 + 64 * 64, cls_W1 };
    const int Ks[NMAT] = {64,64,64,64, 256,64,256,64, 192,192,64,64, 192,192,64,64, 128};
    int offs[NMAT]; int off = 0;
    for (int m = 0; m < NMAT; ++m) { offs[m] = off; off += Ks[m] * 64; }
    for (int m = 0; m < NMAT; ++m) { pa.src[m] = srcs[m]; pa.dstoff[m] = offs[m]; pa.K[m] = Ks[m]; }
    prep_weights<<<NMAT * 64, 256, 0, stream>>>(pa, pool);

    const u16* p_nuW1 = pool + offs[0]; const u16* p_nuW2 = pool + offs[1];
    const u16* p_nbW1 = pool + offs[2]; const u16* p_nbW2 = pool + offs[3];
    const u16* p_euW1 = pool + offs[4]; const u16* p_euW2 = pool + offs[5];
    const u16* p_ebW1 = pool + offs[6]; const u16* p_ebW2 = pool + offs[7];
    const u16* p_u2bW1[2] = { pool + offs[8],  pool + offs[9]  };
    const u16* p_u2bW2[2] = { pool + offs[10], pool + offs[11] };
    const u16* p_b2uW1[2] = { pool + offs[12], pool + offs[13] };
    const u16* p_b2uW2[2] = { pool + offs[14], pool + offs[15] };
    const u16* p_clsW1 = pool + offs[16];

    // ---- node + edge init (node_init also zeroes conv accumulators) ----
    const int nTu = (NU + 127) / 128, nTb = (NB + 127) / 128;
    node_init_both<<<nTu + nTb, 512, 0, stream>>>(
        emb_user, n_id_user, NU, emb_book, n_id_book, NB, nTu,
        p_nuW1, nu_b1, p_nuW2, nu_b2, p_nbW1, nb_b1, p_nbW2, nb_b2,
        hu_b, cuh);
    edge_init_fused<<<(E + 127) / 128, 512, 0, stream>>>(edge_attr, E,
        p_euW1, eu_b1, p_euW2, eu_b2, p_ebW1, eb_b1, p_ebW2, eb_b2, eu_b, eb_b);

    const int n4 = (NU + NB) * 16;          // u16x4 groups of bf16 h
    const int nTe = (E + 127) / 128;
    const int gMsg = 2 * ((nTe + MSG_NITER - 1) / MSG_NITER);
    // ---- conv layers ----
    for (int l = 0; l < 2; ++l) {
        edge_msg_both<<<gMsg, 512, 0, stream>>>(hu_b, hb_b, src, dst,
            eu_b, eb_b, E,
            p_u2bW1[l], cu2b_b1 + l * 64, p_u2bW2[l], cu2b_b2 + l * 64,
            p_b2uW1[l], cb2u_b1 + l * 64, p_b2uW2[l], cb2u_b2 + l * 64,
            cbh, cuh);
        update_kernel<<<1024, 256, 0, stream>>>(hu_b, (__half2*)cuh, n4,
            l == 0 ? 1 : 0, l == 0 ? 1 : 0);
    }

    // ---- classifier ----
    cls_mfma<<<(EL + 127) / 128, 512, 0, stream>>>(hu_b, hb_b, li0, li1, EL,
        p_clsW1, cls_b1, cls_W2, cls_b2, (float*)d_out);
}

// Round 22
// 462.008 us; speedup vs baseline: 1.3004x; 1.0408x over previous
//
// Best verified config (462 us; reproduced x3 in rounds 12/15/17).
// Falsified levers (counter-backed): L1 weights (+139), tile amortization
// (+19), dir-split init (+20), swapped-operand stores (+648), XCD pairing (0),
// barrier halving (0). edge_msg is gather/atomic latency-bound; structural.
#include <hip/hip_runtime.h>
#include <hip/hip_fp16.h>

typedef unsigned short u16;
typedef __attribute__((ext_vector_type(8))) short bf16x8;
typedef __attribute__((ext_vector_type(4))) float f32x4;
typedef __attribute__((ext_vector_type(4))) unsigned short u16x4;

#define NMAT 17

__device__ __forceinline__ u16 f2bf(float f) {
    union { float f; unsigned u; } a; a.f = f;
    unsigned u = a.u;
    return (u16)((u + (((u >> 16) & 1u) + 0x7fffu)) >> 16);
}
__device__ __forceinline__ float bf2f(u16 v) {
    union { unsigned u; float f; } a; a.u = ((unsigned)v) << 16;
    return a.f;
}

// ---------------- weight prep: W[K][64] f32 -> Wt[64][K] bf16 ----------------
struct PrepArgs { const float* src[NMAT]; int dstoff[NMAT]; int K[NMAT]; };

__global__ __launch_bounds__(256) void prep_weights(PrepArgs a, u16* __restrict__ pool) {
    int m = blockIdx.x >> 6;
    int idx = (blockIdx.x & 63) * 256 + threadIdx.x;
    int K = a.K[m];
    if (idx < K * 64) {
        int col = idx / K, k = idx - col * K;
        pool[a.dstoff[m] + idx] = f2bf(a.src[m][(size_t)k * 64 + col]);
    }
}

// ------- node init, BOTH tables; also zero-inits the conv accumulator -------
__global__ __launch_bounds__(512) void node_init_both(
    const float* __restrict__ emb_u, const int* __restrict__ nid_u, int NU_,
    const float* __restrict__ emb_b, const int* __restrict__ nid_b, int NB_, int nTu,
    const u16* __restrict__ W1u, const float* __restrict__ b1u,
    const u16* __restrict__ W2u, const float* __restrict__ b2u,
    const u16* __restrict__ W1b, const float* __restrict__ b1b,
    const u16* __restrict__ W2b, const float* __restrict__ b2b,
    u16* __restrict__ hbf, __half* __restrict__ conv)
{
    __shared__ u16 sW1[64 * 72], sW2[64 * 72], sHid[128 * 72];
    const int tid = threadIdx.x;
    const int wv = tid >> 6, lane = tid & 63;
    const int lr = lane & 15, lk = lane >> 4;

    int t = blockIdx.x;
    const bool isB = t >= nTu;
    if (isB) t -= nTu;
    const int N = isB ? NB_ : NU_;
    const int rowoff = isB ? NU_ : 0;
    const float* emb = isB ? emb_b : emb_u;
    const int* nid = isB ? nid_b : nid_u;
    const u16* W1 = isB ? W1b : W1u;
    const u16* W2 = isB ? W2b : W2u;
    const float* b1 = isB ? b1b : b1u;
    const float* b2 = isB ? b2b : b2u;

    for (int c = tid; c < 512; c += 512) {
        int row = c >> 3, cc = c & 7;
        *(bf16x8*)&sW1[row * 72 + cc * 8] = *(const bf16x8*)&W1[row * 64 + cc * 8];
        *(bf16x8*)&sW2[row * 72 + cc * 8] = *(const bf16x8*)&W2[row * 64 + cc * 8];
    }
    // zero conv rows for this tile
    const int rb0 = t * 128;
    const f32x4 zv = (f32x4){0.f, 0.f, 0.f, 0.f};
#pragma unroll
    for (int c = tid; c < 1024; c += 512) {
        int row = rb0 + (c >> 3), cc = c & 7;
        if (row < N)
            ((f32x4*)&conv[(size_t)(rowoff + row) * 64])[cc] = zv;
    }
    float b1v[4], b2v[4];
#pragma unroll
    for (int n = 0; n < 4; ++n) { b1v[n] = b1[lr + 16 * n]; b2v[n] = b2[lr + 16 * n]; }

    const int rb = t * 128 + wv * 16;
    int ar = rb + lr; if (ar >= N) ar = N - 1;
    const int g = nid[ar];
    const float* ap = emb + (size_t)g * 64 + lk * 8;
    bf16x8 afr[2];
#pragma unroll
    for (int ks = 0; ks < 2; ++ks) {
        f32x4 lo = *(const f32x4*)(ap + ks * 32);
        f32x4 hi = *(const f32x4*)(ap + ks * 32 + 4);
        bf16x8 v;
        v[0] = (short)f2bf(lo[0]); v[1] = (short)f2bf(lo[1]);
        v[2] = (short)f2bf(lo[2]); v[3] = (short)f2bf(lo[3]);
        v[4] = (short)f2bf(hi[0]); v[5] = (short)f2bf(hi[1]);
        v[6] = (short)f2bf(hi[2]); v[7] = (short)f2bf(hi[3]);
        afr[ks] = v;
    }
    __syncthreads();
    f32x4 acc[4];
#pragma unroll
    for (int n = 0; n < 4; ++n) acc[n] = (f32x4){b1v[n], b1v[n], b1v[n], b1v[n]};
#pragma unroll
    for (int ks = 0; ks < 2; ++ks) {
#pragma unroll
        for (int n = 0; n < 4; ++n) {
            bf16x8 bfr = *(const bf16x8*)&sW1[(lr + 16 * n) * 72 + ks * 32 + lk * 8];
            acc[n] = __builtin_amdgcn_mfma_f32_16x16x32_bf16(afr[ks], bfr, acc[n], 0, 0, 0);
        }
    }
#pragma unroll
    for (int n = 0; n < 4; ++n)
#pragma unroll
        for (int i = 0; i < 4; ++i)
            sHid[(wv * 16 + lk * 4 + i) * 72 + lr + 16 * n] = f2bf(fmaxf(acc[n][i], 0.f));
    __syncthreads();
    f32x4 a2[4];
#pragma unroll
    for (int n = 0; n < 4; ++n) a2[n] = (f32x4){b2v[n], b2v[n], b2v[n], b2v[n]};
#pragma unroll
    for (int ks = 0; ks < 2; ++ks) {
        bf16x8 af = *(const bf16x8*)&sHid[(wv * 16 + lr) * 72 + ks * 32 + lk * 8];
#pragma unroll
        for (int n = 0; n < 4; ++n) {
            bf16x8 bfr = *(const bf16x8*)&sW2[(lr + 16 * n) * 72 + ks * 32 + lk * 8];
            a2[n] = __builtin_amdgcn_mfma_f32_16x16x32_bf16(af, bfr, a2[n], 0, 0, 0);
        }
    }
#pragma unroll
    for (int i = 0; i < 4; ++i) {
        int r = rb + lk * 4 + i;
        if (r < N) {
            size_t gr = (size_t)(rowoff + r);
#pragma unroll
            for (int n = 0; n < 4; ++n)
                hbf[gr * 64 + lr + 16 * n] = f2bf(a2[n][i]);
        }
    }
}

// -------- fused edge init: persistent weights, double-buffered sHid ---------
__global__ __launch_bounds__(512) void edge_init_fused(
    const float* __restrict__ attr, int E_,
    const u16* __restrict__ W1u, const float* __restrict__ b1u,
    const u16* __restrict__ W2u, const float* __restrict__ b2u,
    const u16* __restrict__ W1b, const float* __restrict__ b1b,
    const u16* __restrict__ W2b, const float* __restrict__ b2b,
    u16* __restrict__ eu, u16* __restrict__ eb)
{
    __shared__ u16 sW1[2][64 * 264];
    __shared__ u16 sW2[2][64 * 72];
    __shared__ u16 sHid[2][128 * 72];
    const int tid = threadIdx.x;
    const int wv = tid >> 6, lane = tid & 63;
    const int lr = lane & 15, lk = lane >> 4;

    for (int c = tid; c < 4096; c += 512) {
        int d = c >> 11, rem = c & 2047;
        int row = rem >> 5, cc = rem & 31;
        const u16* w = d ? W1b : W1u;
        *(bf16x8*)&sW1[d][row * 264 + cc * 8] = *(const bf16x8*)&w[row * 256 + cc * 8];
    }
    for (int c = tid; c < 1024; c += 512) {
        int d = c >> 9, rem = c & 511;
        int row = rem >> 3, cc = rem & 7;
        const u16* w = d ? W2b : W2u;
        *(bf16x8*)&sW2[d][row * 72 + cc * 8] = *(const bf16x8*)&w[row * 64 + cc * 8];
    }
    float b1v[2][4], b2v[2][4];
#pragma unroll
    for (int n = 0; n < 4; ++n) {
        b1v[0][n] = b1u[lr + 16 * n]; b1v[1][n] = b1b[lr + 16 * n];
        b2v[0][n] = b2u[lr + 16 * n]; b2v[1][n] = b2b[lr + 16 * n];
    }
    __syncthreads();

    const int nT = (E_ + 127) >> 7;
    for (int t = blockIdx.x; t < nT; t += gridDim.x) {
        const int rb = t * 128 + wv * 16;
        int ar = rb + lr; if (ar >= E_) ar = E_ - 1;
        const float* ap = attr + (size_t)ar * 256 + lk * 8;
        bf16x8 afr[8];
#pragma unroll
        for (int ks = 0; ks < 8; ++ks) {
            f32x4 lo = *(const f32x4*)(ap + ks * 32);
            f32x4 hi = *(const f32x4*)(ap + ks * 32 + 4);
            bf16x8 v;
            v[0] = (short)f2bf(lo[0]); v[1] = (short)f2bf(lo[1]);
            v[2] = (short)f2bf(lo[2]); v[3] = (short)f2bf(lo[3]);
            v[4] = (short)f2bf(hi[0]); v[5] = (short)f2bf(hi[1]);
            v[6] = (short)f2bf(hi[2]); v[7] = (short)f2bf(hi[3]);
            afr[ks] = v;
        }
#pragma unroll
        for (int dir = 0; dir < 2; ++dir) {
            f32x4 acc[4];
#pragma unroll
            for (int n = 0; n < 4; ++n) acc[n] = (f32x4){b1v[dir][n], b1v[dir][n], b1v[dir][n], b1v[dir][n]};
#pragma unroll
            for (int ks = 0; ks < 8; ++ks) {
#pragma unroll
                for (int n = 0; n < 4; ++n) {
                    bf16x8 bfr = *(const bf16x8*)&sW1[dir][(lr + 16 * n) * 264 + ks * 32 + lk * 8];
                    acc[n] = __builtin_amdgcn_mfma_f32_16x16x32_bf16(afr[ks], bfr, acc[n], 0, 0, 0);
                }
            }
#pragma unroll
            for (int n = 0; n < 4; ++n)
#pragma unroll
                for (int i = 0; i < 4; ++i)
                    sHid[dir][(wv * 16 + lk * 4 + i) * 72 + lr + 16 * n] = f2bf(fmaxf(acc[n][i], 0.f));
            __syncthreads();
            f32x4 a2[4];
#pragma unroll
            for (int n = 0; n < 4; ++n) a2[n] = (f32x4){b2v[dir][n], b2v[dir][n], b2v[dir][n], b2v[dir][n]};
#pragma unroll
            for (int ks = 0; ks < 2; ++ks) {
                bf16x8 af = *(const bf16x8*)&sHid[dir][(wv * 16 + lr) * 72 + ks * 32 + lk * 8];
#pragma unroll
                for (int n = 0; n < 4; ++n) {
                    bf16x8 bfr = *(const bf16x8*)&sW2[dir][(lr + 16 * n) * 72 + ks * 32 + lk * 8];
                    a2[n] = __builtin_amdgcn_mfma_f32_16x16x32_bf16(af, bfr, a2[n], 0, 0, 0);
                }
            }
            u16* op = dir ? eb : eu;
#pragma unroll
            for (int i = 0; i < 4; ++i) {
                int r = rb + lk * 4 + i;
                if (r < E_) {
#pragma unroll
                    for (int n = 0; n < 4; ++n)
                        op[(size_t)r * 64 + lr + 16 * n] = f2bf(a2[n][i]);
                }
            }
        }
    }
}

// -------- edge messages, both dirs, LDS weights, XCD-paired swizzle ---------
__global__ __launch_bounds__(512) void edge_msg_both(
    const u16* __restrict__ hub, const u16* __restrict__ hbb,
    const int* __restrict__ src, const int* __restrict__ dst,
    const u16* __restrict__ eu, const u16* __restrict__ eb, int E_,
    const u16* __restrict__ W1a, const float* __restrict__ b1a,
    const u16* __restrict__ W2a, const float* __restrict__ b2a,
    const u16* __restrict__ W1b, const float* __restrict__ b1b,
    const u16* __restrict__ W2b, const float* __restrict__ b2b,
    __half* __restrict__ cb, __half* __restrict__ cu)
{
    __shared__ u16 sW1[64 * 200];
    __shared__ u16 sW2[64 * 72];
    __shared__ u16 sHid[128 * 72];
    const int tid = threadIdx.x;
    const int wv = tid >> 6, lane = tid & 63;
    const int lr = lane & 15, lk = lane >> 4;

    const int nTe = (E_ + 127) >> 7;
    const int grp = blockIdx.x >> 4, rem = blockIdx.x & 15;
    const int dir = rem >> 3;
    const int t = grp * 8 + (rem & 7);
    if (t >= nTe) return;

    const u16* W1 = dir ? W1b : W1a;
    const u16* W2 = dir ? W2b : W2a;
    const float* b1 = dir ? b1b : b1a;
    const float* b2 = dir ? b2b : b2a;
    const u16* featA = dir ? hub : hbb;
    const u16* featB = dir ? hbb : hub;
    const int* idxA = dir ? src : dst;
    const int* idxB = dir ? dst : src;
    const u16* eF = dir ? eb : eu;
    __half* out = dir ? cu : cb;

    for (int c = tid; c < 1536; c += 512) {
        int row = c / 24, cc = c - row * 24;
        *(bf16x8*)&sW1[row * 200 + cc * 8] = *(const bf16x8*)&W1[row * 192 + cc * 8];
    }
    for (int c = tid; c < 512; c += 512) {
        int row = c >> 3, cc = c & 7;
        *(bf16x8*)&sW2[row * 72 + cc * 8] = *(const bf16x8*)&W2[row * 64 + cc * 8];
    }
    float b1v[4], b2v[4];
#pragma unroll
    for (int n = 0; n < 4; ++n) { b1v[n] = b1[lr + 16 * n]; b2v[n] = b2[lr + 16 * n]; }

    const int rb = t * 128 + wv * 16;
    int ar = rb + lr; if (ar >= E_) ar = E_ - 1;
    const int ia = idxA[ar], ib = idxB[ar];
    bf16x8 aseq[6];
    aseq[0] = *(const bf16x8*)&featA[(size_t)ia * 64 + lk * 8];
    aseq[1] = *(const bf16x8*)&featA[(size_t)ia * 64 + 32 + lk * 8];
    aseq[2] = *(const bf16x8*)&featB[(size_t)ib * 64 + lk * 8];
    aseq[3] = *(const bf16x8*)&featB[(size_t)ib * 64 + 32 + lk * 8];
    aseq[4] = *(const bf16x8*)&eF[(size_t)ar * 64 + lk * 8];
    aseq[5] = *(const bf16x8*)&eF[(size_t)ar * 64 + 32 + lk * 8];
    __syncthreads();   // sW1/sW2 staged
    f32x4 acc[4];
#pragma unroll
    for (int n = 0; n < 4; ++n) acc[n] = (f32x4){b1v[n], b1v[n], b1v[n], b1v[n]};
#pragma unroll
    for (int ks = 0; ks < 6; ++ks) {
#pragma unroll
        for (int n = 0; n < 4; ++n) {
            bf16x8 bfr = *(const bf16x8*)&sW1[(lr + 16 * n) * 200 + ks * 32 + lk * 8];
            acc[n] = __builtin_amdgcn_mfma_f32_16x16x32_bf16(aseq[ks], bfr, acc[n], 0, 0, 0);
        }
    }
#pragma unroll
    for (int n = 0; n < 4; ++n)
#pragma unroll
        for (int i = 0; i < 4; ++i)
            sHid[(wv * 16 + lk * 4 + i) * 72 + lr + 16 * n] = f2bf(fmaxf(acc[n][i], 0.f));
    __syncthreads();
    f32x4 a2[4];
#pragma unroll
    for (int n = 0; n < 4; ++n) a2[n] = (f32x4){b2v[n], b2v[n], b2v[n], b2v[n]};
#pragma unroll
    for (int ks = 0; ks < 2; ++ks) {
        bf16x8 af = *(const bf16x8*)&sHid[(wv * 16 + lr) * 72 + ks * 32 + lk * 8];
#pragma unroll
        for (int n = 0; n < 4; ++n) {
            bf16x8 bfr = *(const bf16x8*)&sW2[(lr + 16 * n) * 72 + ks * 32 + lk * 8];
            a2[n] = __builtin_amdgcn_mfma_f32_16x16x32_bf16(af, bfr, a2[n], 0, 0, 0);
        }
    }
    // ---- pair even/odd channels across lane pairs; 8 half2 atomics/lane ----
    const bool odd = (lr & 1) != 0;
    float lov[4][2], hiv[4][2];
#pragma unroll
    for (int n = 0; n < 4; ++n) {
        float o0 = __shfl_xor(a2[n][0], 1);
        float o1 = __shfl_xor(a2[n][1], 1);
        float o2 = __shfl_xor(a2[n][2], 1);
        float o3 = __shfl_xor(a2[n][3], 1);
        lov[n][0] = odd ? o2 : a2[n][0];
        hiv[n][0] = odd ? a2[n][2] : o0;
        lov[n][1] = odd ? o3 : a2[n][1];
        hiv[n][1] = odd ? a2[n][3] : o1;
    }
    const int ibase = odd ? 2 : 0;
    const int cpair = lr & ~1;
#pragma unroll
    for (int k = 0; k < 2; ++k) {
        int r = rb + lk * 4 + ibase + k;
        if (r < E_) {
            const int o = idxA[r];
            __half* bp = out + (size_t)o * 64 + cpair;
#pragma unroll
            for (int n = 0; n < 4; ++n)
                unsafeAtomicAdd((__half2*)(bp + 16 * n),
                                __floats2half2_rn(lov[n][k], hiv[n][k]));
        }
    }
}

// ------- update on bf16 h-state; optionally re-zeroes conv ------------------
__global__ void update_kernel(u16* __restrict__ hbf, __half2* __restrict__ c2,
                              int n4, int relu_res, int zero_next)
{
    const int st = gridDim.x * blockDim.x;
    const __half2 hz = __floats2half2_rn(0.f, 0.f);
    for (int j = blockIdx.x * blockDim.x + threadIdx.x; j < n4; j += st) {
        u16x4 hp = ((const u16x4*)hbf)[j];
        float2 f0 = __half22float2(c2[2 * j]);
        float2 f1 = __half22float2(c2[2 * j + 1]);
        if (zero_next) { c2[2 * j] = hz; c2[2 * j + 1] = hz; }
        float v0, v1, v2, v3;
        if (relu_res) {
            v0 = fmaxf(fmaf(bf2f(hp[0]), 2.1f, f0.x), 0.f);
            v1 = fmaxf(fmaf(bf2f(hp[1]), 2.1f, f0.y), 0.f);
            v2 = fmaxf(fmaf(bf2f(hp[2]), 2.1f, f1.x), 0.f);
            v3 = fmaxf(fmaf(bf2f(hp[3]), 2.1f, f1.y), 0.f);
        } else {
            v0 = fmaf(bf2f(hp[0]), 1.1f, f0.x);
            v1 = fmaf(bf2f(hp[1]), 1.1f, f0.y);
            v2 = fmaf(bf2f(hp[2]), 1.1f, f1.x);
            v3 = fmaf(bf2f(hp[3]), 1.1f, f1.y);
        }
        u16x4 p;
        p[0] = f2bf(v0); p[1] = f2bf(v1); p[2] = f2bf(v2); p[3] = f2bf(v3);
        ((u16x4*)hbf)[j] = p;
    }
}

// ---------------- classifier ------------------------------------------------
__global__ __launch_bounds__(512) void cls_mfma(
    const u16* __restrict__ hub, const u16* __restrict__ hbb,
    const int* __restrict__ i0, const int* __restrict__ i1, int EL_,
    const u16* __restrict__ W1, const float* __restrict__ b1,
    const float* __restrict__ W2, const float* __restrict__ b2,
    float* __restrict__ out)
{
    __shared__ u16 sW1[64 * 136];
    const int tid = threadIdx.x;
    const int wv = tid >> 6, lane = tid & 63;
    const int lr = lane & 15, lk = lane >> 4;
    for (int c = tid; c < 1024; c += 512) {
        int row = c >> 4, cc = c & 15;
        *(bf16x8*)&sW1[row * 136 + cc * 8] = *(const bf16x8*)&W1[row * 128 + cc * 8];
    }
    float b1v[4], w2v[4];
#pragma unroll
    for (int n = 0; n < 4; ++n) { b1v[n] = b1[lr + 16 * n]; w2v[n] = W2[lr + 16 * n]; }
    const float b2s = b2[0];
    __syncthreads();

    const int nT = (EL_ + 127) >> 7;
    for (int t = blockIdx.x; t < nT; t += gridDim.x) {
        const int rb = t * 128 + wv * 16;
        int ar = rb + lr; if (ar >= EL_) ar = EL_ - 1;
        const int gu = i0[ar], gb = i1[ar];
        bf16x8 af[4];
        af[0] = *(const bf16x8*)&hub[(size_t)gu * 64 + lk * 8];
        af[1] = *(const bf16x8*)&hub[(size_t)gu * 64 + 32 + lk * 8];
        af[2] = *(const bf16x8*)&hbb[(size_t)gb * 64 + lk * 8];
        af[3] = *(const bf16x8*)&hbb[(size_t)gb * 64 + 32 + lk * 8];
        f32x4 acc[4];
#pragma unroll
        for (int n = 0; n < 4; ++n) acc[n] = (f32x4){b1v[n], b1v[n], b1v[n], b1v[n]};
#pragma unroll
        for (int ks = 0; ks < 4; ++ks) {
#pragma unroll
            for (int n = 0; n < 4; ++n) {
                bf16x8 bfr = *(const bf16x8*)&sW1[(lr + 16 * n) * 136 + ks * 32 + lk * 8];
                acc[n] = __builtin_amdgcn_mfma_f32_16x16x32_bf16(af[ks], bfr, acc[n], 0, 0, 0);
            }
        }
#pragma unroll
        for (int i = 0; i < 4; ++i) {
            float v = 0.f;
#pragma unroll
            for (int n = 0; n < 4; ++n) v = fmaf(fmaxf(acc[n][i], 0.f), w2v[n], v);
            v += __shfl_xor(v, 1); v += __shfl_xor(v, 2);
            v += __shfl_xor(v, 4); v += __shfl_xor(v, 8);
            int r = rb + lk * 4 + i;
            if (lr == 0 && r < EL_) out[r] = v + b2s;
        }
    }
}

extern "C" void kernel_launch(void* const* d_in, const int* in_sizes, int n_in,
                              void* d_out, int out_size, void* d_ws, size_t ws_size,
                              hipStream_t stream)
{
    const float* emb_user = (const float*)d_in[0];
    const float* emb_book = (const float*)d_in[1];
    const float* nu_W1 = (const float*)d_in[2];
    const float* nu_b1 = (const float*)d_in[3];
    const float* nu_W2 = (const float*)d_in[4];
    const float* nu_b2 = (const float*)d_in[5];
    const float* nb_W1 = (const float*)d_in[6];
    const float* nb_b1 = (const float*)d_in[7];
    const float* nb_W2 = (const float*)d_in[8];
    const float* nb_b2 = (const float*)d_in[9];
    const float* eu_W1 = (const float*)d_in[10];
    const float* eu_b1 = (const float*)d_in[11];
    const float* eu_W2 = (const float*)d_in[12];
    const float* eu_b2 = (const float*)d_in[13];
    const float* eb_W1 = (const float*)d_in[14];
    const float* eb_b1 = (const float*)d_in[15];
    const float* eb_W2 = (const float*)d_in[16];
    const float* eb_b2 = (const float*)d_in[17];
    const float* cu2b_W1 = (const float*)d_in[18];
    const float* cu2b_b1 = (const float*)d_in[19];
    const float* cu2b_W2 = (const float*)d_in[20];
    const float* cu2b_b2 = (const float*)d_in[21];
    const float* cb2u_W1 = (const float*)d_in[22];
    const float* cb2u_b1 = (const float*)d_in[23];
    const float* cb2u_W2 = (const float*)d_in[24];
    const float* cb2u_b2 = (const float*)d_in[25];
    const float* cls_W1 = (const float*)d_in[26];
    const float* cls_b1 = (const float*)d_in[27];
    const float* cls_W2 = (const float*)d_in[28];
    const float* cls_b2 = (const float*)d_in[29];
    const float* edge_attr = (const float*)d_in[30];
    const int* n_id_user = (const int*)d_in[31];
    const int* n_id_book = (const int*)d_in[32];
    const int* edge_index = (const int*)d_in[33];
    const int* edge_label_index = (const int*)d_in[34];

    const int NU = in_sizes[31];
    const int NB = in_sizes[32];
    const int E  = in_sizes[33] / 2;
    const int EL = in_sizes[34] / 2;

    const int* src = edge_index;
    const int* dst = edge_index + E;
    const int* li0 = edge_label_index;
    const int* li1 = edge_label_index + EL;

    // workspace layout (no f32 h state)
    __half* cuh = (__half*)d_ws;                       // NU*64 f16
    __half* cbh = cuh + (size_t)NU * 64;               // NB*64 f16
    u16* hu_b = (u16*)(cbh + (size_t)NB * 64);         // NU*64 bf16
    u16* hb_b = hu_b + (size_t)NU * 64;                // NB*64 bf16
    u16* eu_b = hb_b + (size_t)NB * 64;                // E*64 bf16
    u16* eb_b = eu_b + (size_t)E * 64;                 // E*64 bf16
    u16* pool = eb_b + (size_t)E * 64;

    // ---- weight prep ----
    PrepArgs pa;
    const float* srcs[NMAT] = { nu_W1, nu_W2, nb_W1, nb_W2, eu_W1, eu_W2, eb_W1, eb_W2,
        cu2b_W1, cu2b_W1 + 192 * 64, cu2b_W2, cu2b_W2 + 64 * 64,
        cb2u_W1, cb2u_W1 + 192 * 64, cb2u_W2, cb2u_W2 + 64 * 64, cls_W1 };
    const int Ks[NMAT] = {64,64,64,64, 256,64,256,64, 192,192,64,64, 192,192,64,64, 128};
    int offs[NMAT]; int off = 0;
    for (int m = 0; m < NMAT; ++m) { offs[m] = off; off += Ks[m] * 64; }
    for (int m = 0; m < NMAT; ++m) { pa.src[m] = srcs[m]; pa.dstoff[m] = offs[m]; pa.K[m] = Ks[m]; }
    prep_weights<<<NMAT * 64, 256, 0, stream>>>(pa, pool);

    const u16* p_nuW1 = pool + offs[0]; const u16* p_nuW2 = pool + offs[1];
    const u16* p_nbW1 = pool + offs[2]; const u16* p_nbW2 = pool + offs[3];
    const u16* p_euW1 = pool + offs[4]; const u16* p_euW2 = pool + offs[5];
    const u16* p_ebW1 = pool + offs[6]; const u16* p_ebW2 = pool + offs[7];
    const u16* p_u2bW1[2] = { pool + offs[8],  pool + offs[9]  };
    const u16* p_u2bW2[2] = { pool + offs[10], pool + offs[11] };
    const u16* p_b2uW1[2] = { pool + offs[12], pool + offs[13] };
    const u16* p_b2uW2[2] = { pool + offs[14], pool + offs[15] };
    const u16* p_clsW1 = pool + offs[16];

    // ---- node + edge init (node_init also zeroes conv accumulators) ----
    const int nTu = (NU + 127) / 128, nTb = (NB + 127) / 128;
    node_init_both<<<nTu + nTb, 512, 0, stream>>>(
        emb_user, n_id_user, NU, emb_book, n_id_book, NB, nTu,
        p_nuW1, nu_b1, p_nuW2, nu_b2, p_nbW1, nb_b1, p_nbW2, nb_b2,
        hu_b, cuh);
    edge_init_fused<<<(E + 127) / 128, 512, 0, stream>>>(edge_attr, E,
        p_euW1, eu_b1, p_euW2, eu_b2, p_ebW1, eb_b1, p_ebW2, eb_b2, eu_b, eb_b);

    const int n4 = (NU + NB) * 16;          // u16x4 groups of bf16 h
    const int nTe = (E + 127) / 128;
    const int gMsg = ((nTe + 7) / 8) * 16;  // XCD-paired swizzle grid
    // ---- conv layers ----
    for (int l = 0; l < 2; ++l) {
        edge_msg_both<<<gMsg, 512, 0, stream>>>(hu_b, hb_b, src, dst,
            eu_b, eb_b, E,
            p_u2bW1[l], cu2b_b1 + l * 64, p_u2bW2[l], cu2b_b2 + l * 64,
            p_b2uW1[l], cb2u_b1 + l * 64, p_b2uW2[l], cb2u_b2 + l * 64,
            cbh, cuh);
        update_kernel<<<1024, 256, 0, stream>>>(hu_b, (__half2*)cuh, n4,
            l == 0 ? 1 : 0, l == 0 ? 1 : 0);
    }

    // ---- classifier ----
    cls_mfma<<<(EL + 127) / 128, 512, 0, stream>>>(hu_b, hb_b, li0, li1, EL,
        p_clsW1, cls_b1, cls_W2, cls_b2, (float*)d_out);
}